// Round 7
// baseline (11586.721 us; speedup 1.0000x reference)
//
#include <hip/hip_runtime.h>
#include <hip/hip_bf16.h>

// Problem constants
#define T_ 512
#define B_ 256
#define I_ 128
#define H_ 256
#define NB_ 16     // batch groups (16 rows each)
#define RING_D 8   // h0 ring depth (L0 lead over L1)
#define SPIN_MAX (1 << 17)

typedef unsigned short ushort_t;
typedef unsigned int uint_t;
typedef unsigned long long u64_t;
typedef __attribute__((ext_vector_type(8))) short short8;  // 8 bf16 (4 VGPRs)
typedef __attribute__((ext_vector_type(4))) float f32x4;

// ws layout: ring u32 [16 g][RING_D][16 rows][256 cols], each u32 = hi|mid<<16 bf16 pair
#define RING_U32 (16 * RING_D * 16 * 256)   // 524288 u32 = 2 MB
// flags (int) after ring:
//  [g*16]        : slot0 (h0[t] published => t+1)
//  [256 + g*16]  : slot1 (L1 consumed h0[t] => t+1)
//  [512 + bid]   : xcd id per block
//  [768 + g*16]  : per-group arrival counter
#define N_FLAGS 1024

__device__ __forceinline__ ushort_t f2bf(float f) {  // RNE f32->bf16
  unsigned int u = __float_as_uint(f);
  u += 0x7fffu + ((u >> 16) & 1u);
  return (ushort_t)(u >> 16);
}
__device__ __forceinline__ float bf2f(ushort_t u) {
  return __uint_as_float(((unsigned int)u) << 16);
}

__global__ void prep_kernel(int* __restrict__ flags) {
  int i = threadIdx.x;
  if (i < N_FLAGS) flags[i] = 0;
}

// ---------------- fragment helpers (verified gfx950 16x16x32 layouts) ----------------
// A/B frag: element j of lane l maps to [m|n = l&15][k = (l>>4)*8 + j]
struct frag2 { short8 h, m; };

// split fp32 (16B-aligned, 8 consecutive) into 2 bf16 fragments (~2^-18 rel error)
__device__ __forceinline__ frag2 split2(const float* p) {
  f32x4 a = *(const f32x4*)p;
  f32x4 b = *(const f32x4*)(p + 4);
  float v[8] = {a[0], a[1], a[2], a[3], b[0], b[1], b[2], b[3]};
  frag2 r;
#pragma unroll
  for (int j = 0; j < 8; j++) {
    float f = v[j];
    ushort_t x = f2bf(f); f -= bf2f(x);
    ushort_t y = f2bf(f);
    r.h[j] = (short)x; r.m[j] = (short)y;
  }
  return r;
}
// x A-frag (2-plane) from fp32
__device__ __forceinline__ frag2 lda_x2(const float* base, int ldk, int kc, int lane) {
  return split2(base + (size_t)(lane & 15) * ldk + kc * 32 + ((lane >> 4) << 3));
}
// 1-plane weight B-frag: W[row + n][kc*32 + quad*8 + j], RNE bf16
__device__ __forceinline__ short8 ldw1(const float* base, int ldk, int row, int kc, int lane) {
  const float* p = base + (size_t)(row + (lane & 15)) * ldk + kc * 32 + ((lane >> 4) << 3);
  f32x4 a = *(const f32x4*)p;
  f32x4 b = *(const f32x4*)(p + 4);
  short8 r;
  r[0] = (short)f2bf(a[0]); r[1] = (short)f2bf(a[1]);
  r[2] = (short)f2bf(a[2]); r[3] = (short)f2bf(a[3]);
  r[4] = (short)f2bf(b[0]); r[5] = (short)f2bf(b[1]);
  r[6] = (short)f2bf(b[2]); r[7] = (short)f2bf(b[3]);
  return r;
}
#define CFENCE() asm volatile("" ::: "memory")

__device__ __forceinline__ f32x4 mfma_(short8 a, short8 b, f32x4 c) {
  return __builtin_amdgcn_mfma_f32_16x16x32_bf16(a, b, c, 0, 0, 0);
}
// poll single flag (uniform addr across threads; tracked relaxed agent load -> sc0)
__device__ __forceinline__ int poll1(const int* p, int tgt, int aborted) {
  if (aborted || tgt <= 0) return aborted;
  int n = 0;
  while (__hip_atomic_load(p, __ATOMIC_RELAXED, __HIP_MEMORY_SCOPE_AGENT) < tgt) {
    if (++n > SPIN_MAX) return 1;
  }
  return 0;
}
__device__ __forceinline__ int get_xcc() {
  int x;
  asm volatile("s_getreg_b32 %0, hwreg(HW_REG_XCC_ID)" : "=s"(x));
  return x & 15;
}
// GRU pointwise, hand-coded transcendentals (v_exp_f32 + v_rcp_f32; ~1ulp each)
__device__ __forceinline__ float cellpw_fast(float gr, float gz, float np, float h) {
  float r = __builtin_amdgcn_rcpf(1.0f + __builtin_amdgcn_exp2f(-1.44269504089f * gr));
  float z = __builtin_amdgcn_rcpf(1.0f + __builtin_amdgcn_exp2f(-1.44269504089f * gz));
  float a = np + r * h;
  float n = 1.0f - 2.0f * __builtin_amdgcn_rcpf(1.0f + __builtin_amdgcn_exp2f(2.88539008177f * a));
  return (1.0f - z) * n + z * h;
}

// ---------------- persistent kernel: 32 WGs x 1024 threads (1/CU, 16 waves) ----------
// Block g      (role 0): full layer-0 cell for batch group g. Recurrence intra-WG
//                        (LDS + 1 barrier/step). Publishes h0[t] to L2 ring.
// Block 16+g   (role 1): full layer-1 cell for group g; consumes ring, lags ~1 step.
// Wave wv owns gate cols [wv*16, wv*16+16): r, z, n accumulators stay in-wave.
__global__ void __launch_bounds__(1024, 1)
gru_main(const float* __restrict__ x,
         const float* __restrict__ Wi0, const float* __restrict__ Wh0, const float* __restrict__ Wn0,
         const float* __restrict__ Wi1, const float* __restrict__ Wh1, const float* __restrict__ Wn1,
         const float* __restrict__ state, float* __restrict__ out,
         uint_t* __restrict__ ring, int* __restrict__ flags) {
  __shared__ alignas(16) ushort_t hbuf[2][2][16][264];  // [buf][plane][row][col+pad]
  __shared__ float hown[16][257];                       // fp32 carry, padded
  __shared__ int s_fast;

  const int tid = (int)threadIdx.x;
  const int lane = tid & 63;
  const int wv = tid >> 6;                 // wave 0..15
  const int bid = (int)blockIdx.x;
  const int g = bid & 15;                  // group; blocks g and 16+g share XCD (bid%8)
  const int role = bid >> 4;               // 0 = layer0, 1 = layer1
  const int gb = g * 16;
  const int c0 = wv * 16;                  // this wave's gate-col base
  const int q = lane >> 4;
  const int pcol = c0 + (lane & 15);       // this thread's output col
  const int arow = lane & 15;              // A-frag row
  const int acol = (lane >> 4) << 3;       // A-frag k sub-offset

  int* slot0 = flags + g * 16;
  int* slot1 = flags + 256 + g * 16;

  // ---- one-time pair XCD-locality check (L0-WG vs L1-WG of this group) ----
  if (tid == 0) {
    int myx = get_xcc();
    __hip_atomic_store(&flags[512 + bid], myx, __ATOMIC_RELAXED, __HIP_MEMORY_SCOPE_AGENT);
    __threadfence();
    __hip_atomic_fetch_add(&flags[768 + g * 16], 1, __ATOMIC_RELEASE, __HIP_MEMORY_SCOPE_AGENT);
    int n = 0, ab = 0;
    while (__hip_atomic_load(&flags[768 + g * 16], __ATOMIC_RELAXED,
                             __HIP_MEMORY_SCOPE_AGENT) < 2) {
      if (++n > SPIN_MAX) { ab = 1; break; }
    }
    __threadfence();
    int ox = __hip_atomic_load(&flags[512 + (bid ^ 16)], __ATOMIC_RELAXED,
                               __HIP_MEMORY_SCOPE_AGENT);
    s_fast = (!ab && ox == myx) ? 1 : 0;
  }

  // ---- init h[-1] (own layer's state) into hown + hbuf[0] ----
  {
    const float* st = state + (size_t)role * B_ * H_;
#pragma unroll
    for (int r = 0; r < 4; r++) {
      int brow = q * 4 + r;
      float f = st[(size_t)(gb + brow) * H_ + pcol];
      hown[brow][pcol] = f;
      ushort_t hi = f2bf(f);
      ushort_t mid = f2bf(f - bf2f(hi));
      hbuf[0][0][brow][pcol] = hi;
      hbuf[0][1][brow][pcol] = mid;
    }
  }

  int aborted = 0;
  const f32x4 zz = {0.f, 0.f, 0.f, 0.f};

  if (role == 0) {
    //============ layer-0 WG: whole cell per step, intra-WG recurrence ============
    // stationary weights (1-plane bf16): 112 VGPRs/thread
    short8 Wr[12], Wz[12], Wn[4];
#pragma unroll
    for (int kc = 0; kc < 4; kc++) Wr[kc] = ldw1(Wi0, I_, c0, kc, lane);
#pragma unroll
    for (int kc = 0; kc < 8; kc++) Wr[4 + kc] = ldw1(Wh0, H_, c0, kc, lane);
#pragma unroll
    for (int kc = 0; kc < 4; kc++) Wz[kc] = ldw1(Wi0, I_, 256 + c0, kc, lane);
#pragma unroll
    for (int kc = 0; kc < 8; kc++) Wz[4 + kc] = ldw1(Wh0, H_, 256 + c0, kc, lane);
#pragma unroll
    for (int kc = 0; kc < 4; kc++) Wn[kc] = ldw1(Wn0, I_, c0, kc, lane);
    __syncthreads();
    const int fast = s_fast;

    for (int t = 0; t < T_; t++) {
      const int p = t & 1;
      f32x4 accr = zz, accz = zz, accn = zz;
      // h-part from LDS (2-plane h x 1-plane W = 2 MFMA per kc per gate)
      const ushort_t* bh = &hbuf[p][0][0][0];
      const ushort_t* bm = &hbuf[p][1][0][0];
#pragma unroll
      for (int kc = 0; kc < 8; kc++) {
        short8 ah = *(const short8*)(bh + arow * 264 + kc * 32 + acol);
        short8 am = *(const short8*)(bm + arow * 264 + kc * 32 + acol);
        accr = mfma_(ah, Wr[4 + kc], accr); accr = mfma_(am, Wr[4 + kc], accr);
        accz = mfma_(ah, Wz[4 + kc], accz); accz = mfma_(am, Wz[4 + kc], accz);
      }
      // x-part (global, L3-resident; hidden under h-part MFMAs)
      const float* xt = x + ((size_t)t * B_ + gb) * I_;
#pragma unroll
      for (int kc = 0; kc < 4; kc++) {
        frag2 a = lda_x2(xt, I_, kc, lane);
        accr = mfma_(a.h, Wr[kc], accr); accr = mfma_(a.m, Wr[kc], accr);
        accz = mfma_(a.h, Wz[kc], accz); accz = mfma_(a.m, Wz[kc], accz);
        accn = mfma_(a.h, Wn[kc], accn); accn = mfma_(a.m, Wn[kc], accn);
      }
      // ring WAR: L1 must have consumed h0[t-RING_D] (normally far behind-proof)
      if (t >= RING_D) aborted = poll1(slot1, t - (RING_D - 1), aborted);
      CFENCE();
      uint_t* rw = ring + ((size_t)g * RING_D + (size_t)(t & (RING_D - 1))) * (16 * 256);
#pragma unroll
      for (int r = 0; r < 4; r++) {
        int brow = q * 4 + r;
        float h = hown[brow][pcol];
        float hn = cellpw_fast(accr[r], accz[r], accn[r], h);
        hown[brow][pcol] = hn;
        ushort_t hi = f2bf(hn);
        ushort_t mid = f2bf(hn - bf2f(hi));
        hbuf[p ^ 1][0][brow][pcol] = hi;
        hbuf[p ^ 1][1][brow][pcol] = mid;
        rw[brow * 256 + pcol] = (uint_t)hi | ((uint_t)mid << 16);  // packed publish
      }
      __syncthreads();  // orders LDS for next step + drains ring stores (vmcnt)
      if (tid == 0) {
        if (!fast) __threadfence();
        __hip_atomic_store(slot0, t + 1, __ATOMIC_RELAXED, __HIP_MEMORY_SCOPE_AGENT);
      }
    }
    // final h0 state
#pragma unroll
    for (int r = 0; r < 4; r++) {
      int brow = q * 4 + r;
      out[(size_t)T_ * B_ * H_ + (size_t)(gb + brow) * H_ + pcol] = hown[brow][pcol];
    }
  } else {
    //============ layer-1 WG: consumes h0 ring, intra-WG h1 recurrence ============
    // stationary weights: 160 VGPRs/thread
    short8 Wr[16], Wz[16], Wn[8];
#pragma unroll
    for (int kc = 0; kc < 8; kc++) Wr[kc] = ldw1(Wi1, H_, c0, kc, lane);        // Q-side
#pragma unroll
    for (int kc = 0; kc < 8; kc++) Wr[8 + kc] = ldw1(Wh1, H_, c0, kc, lane);    // R-side
#pragma unroll
    for (int kc = 0; kc < 8; kc++) Wz[kc] = ldw1(Wi1, H_, 256 + c0, kc, lane);
#pragma unroll
    for (int kc = 0; kc < 8; kc++) Wz[8 + kc] = ldw1(Wh1, H_, 256 + c0, kc, lane);
#pragma unroll
    for (int kc = 0; kc < 8; kc++) Wn[kc] = ldw1(Wn1, H_, c0, kc, lane);
    __syncthreads();
    const int fast = s_fast;

    for (int t = 0; t < T_; t++) {
      const int p = t & 1;
      f32x4 accr = zz, accz = zz, accn = zz;
      // R-side (h1[t-1], own LDS) first: independent of L0
      const ushort_t* bh = &hbuf[p][0][0][0];
      const ushort_t* bm = &hbuf[p][1][0][0];
#pragma unroll
      for (int kc = 0; kc < 8; kc++) {
        short8 rh = *(const short8*)(bh + arow * 264 + kc * 32 + acol);
        short8 rm = *(const short8*)(bm + arow * 264 + kc * 32 + acol);
        accr = mfma_(rh, Wr[8 + kc], accr); accr = mfma_(rm, Wr[8 + kc], accr);
        accz = mfma_(rh, Wz[8 + kc], accz); accz = mfma_(rm, Wz[8 + kc], accz);
      }
      // wait h0[t] (usually already published; single-line broadcast poll)
      aborted = poll1(slot0, t + 1, aborted);
      if (!fast) __threadfence();
      CFENCE();
      const uint_t* rr = ring + ((size_t)g * RING_D + (size_t)(t & (RING_D - 1))) * (16 * 256)
                         + (size_t)arow * 256 + acol;
#pragma unroll
      for (int kc = 0; kc < 8; kc++) {
        const u64_t* qp = (const u64_t*)(rr + kc * 32);
        u64_t d[4];
        d[0] = __hip_atomic_load(qp + 0, __ATOMIC_RELAXED, __HIP_MEMORY_SCOPE_AGENT);
        d[1] = __hip_atomic_load(qp + 1, __ATOMIC_RELAXED, __HIP_MEMORY_SCOPE_AGENT);
        d[2] = __hip_atomic_load(qp + 2, __ATOMIC_RELAXED, __HIP_MEMORY_SCOPE_AGENT);
        d[3] = __hip_atomic_load(qp + 3, __ATOMIC_RELAXED, __HIP_MEMORY_SCOPE_AGENT);
        short8 qh, qm;
#pragma unroll
        for (int j = 0; j < 4; j++) {
          uint_t lo = (uint_t)d[j];
          uint_t h2 = (uint_t)(d[j] >> 32);
          qh[2 * j]     = (short)(lo & 0xffffu); qm[2 * j]     = (short)(lo >> 16);
          qh[2 * j + 1] = (short)(h2 & 0xffffu); qm[2 * j + 1] = (short)(h2 >> 16);
        }
        accr = mfma_(qh, Wr[kc], accr); accr = mfma_(qm, Wr[kc], accr);
        accz = mfma_(qh, Wz[kc], accz); accz = mfma_(qm, Wz[kc], accz);
        accn = mfma_(qh, Wn[kc], accn); accn = mfma_(qm, Wn[kc], accn);
      }
      float hnv[4];
#pragma unroll
      for (int r = 0; r < 4; r++) {
        int brow = q * 4 + r;
        float h = hown[brow][pcol];
        float hn = cellpw_fast(accr[r], accz[r], accn[r], h);
        hown[brow][pcol] = hn;
        ushort_t hi = f2bf(hn);
        ushort_t mid = f2bf(hn - bf2f(hi));
        hbuf[p ^ 1][0][brow][pcol] = hi;
        hbuf[p ^ 1][1][brow][pcol] = mid;
        hnv[r] = hn;
      }
      __syncthreads();  // ring loads done + LDS ordered
      if (tid == 0) {
        if (!fast) __threadfence();
        __hip_atomic_store(slot1, t + 1, __ATOMIC_RELAXED, __HIP_MEMORY_SCOPE_AGENT);
      }
      // out[t] HBM stores AFTER the bump: drain overlaps next step's compute
#pragma unroll
      for (int r = 0; r < 4; r++) {
        out[((size_t)t * B_ + gb + q * 4 + r) * H_ + pcol] = hnv[r];
      }
    }
    // final h1 state
#pragma unroll
    for (int r = 0; r < 4; r++) {
      int brow = q * 4 + r;
      out[(size_t)T_ * B_ * H_ + (size_t)B_ * H_ + (size_t)(gb + brow) * H_ + pcol] =
          hown[brow][pcol];
    }
  }

  // diagnostic sentinel: spin abort signature
  if (tid == 0 && aborted) out[(size_t)gb * H_] = 4096.0f;
}

extern "C" void kernel_launch(void* const* d_in, const int* in_sizes, int n_in,
                              void* d_out, int out_size, void* d_ws, size_t ws_size,
                              hipStream_t stream) {
  const float* x     = (const float*)d_in[0];
  const float* state = (const float*)d_in[1];
  const float* Wi0   = (const float*)d_in[2];
  const float* Wh0   = (const float*)d_in[3];
  const float* Wn0   = (const float*)d_in[4];
  const float* Wi1   = (const float*)d_in[5];
  const float* Wh1   = (const float*)d_in[6];
  const float* Wn1   = (const float*)d_in[7];
  float* out = (float*)d_out;
  uint_t* ring = (uint_t*)d_ws;
  int* flags = (int*)((char*)d_ws + (size_t)RING_U32 * 4);

  prep_kernel<<<dim3(1), dim3(1024), 0, stream>>>(flags);

  gru_main<<<dim3(2 * NB_), dim3(1024), 0, stream>>>(
      x, Wi0, Wh0, Wn0, Wi1, Wh1, Wn1, state, out, ring, flags);
}

// Round 8
// 5370.304 us; speedup vs baseline: 2.1576x; 2.1576x over previous
//
#include <hip/hip_runtime.h>

// Problem constants
#define T_ 512
#define B_ 256
#define I_ 128
#define H_ 256
#define SPIN_MAX (1 << 18)

typedef unsigned short ushort_t;
typedef unsigned int uint_t;
typedef unsigned long long u64_t;
typedef __attribute__((ext_vector_type(8))) short short8;  // 8 bf16 (4 VGPRs)
typedef __attribute__((ext_vector_type(4))) float f32x4;

// ws layout (u32 units). h stored PACKED: u32 = hi_bf16 | mid_bf16<<16 (2-plane).
// ring0[g][4][16 rows][256 cols]  : h0 ring, 4 deep   -> 16*4*4096 = 262144 u32
// h1buf[g][2][16 rows][256 cols]  : h1 double buffer  -> 16*2*4096 = 131072 u32
#define RING0_OFF 0
#define H1_OFF    262144
#define FLAGS_OFF 393216
// flags (int):
//  [g*16 + ws]       slots0 : wave ws of L0 published h0[t] => t+1
//  [256 + g*16 + ws] slots1 : wave ws of L1 published h1[t] => t+1
//  [512 + bid]       xcd id per block
//  [768 + g*16]      per-group arrival counter
#define N_FLAGS 1024

__device__ __forceinline__ ushort_t f2bf(float f) {  // RNE f32->bf16
  unsigned int u = __float_as_uint(f);
  u += 0x7fffu + ((u >> 16) & 1u);
  return (ushort_t)(u >> 16);
}
__device__ __forceinline__ float bf2f(ushort_t u) {
  return __uint_as_float(((unsigned int)u) << 16);
}

// ---------------- prep: state -> packed planes + flag zeroing ----------------
__global__ void prep_kernel(const float* __restrict__ state, uint_t* __restrict__ ws) {
  int i = blockIdx.x * 256 + threadIdx.x;
  if (i < 131072) {
    int which = i >> 16;          // 0: h0 state, 1: h1 state
    int j = i & 65535;
    int b = j >> 8, col = j & 255;
    int g = b >> 4, row = b & 15;
    float f = state[i];
    ushort_t hi = f2bf(f);
    ushort_t mid = f2bf(f - bf2f(hi));
    uint_t v = (uint_t)hi | ((uint_t)mid << 16);
    if (which == 0) ws[RING0_OFF + ((size_t)g * 4 + 3) * 4096 + row * 256 + col] = v;  // h0[-1] -> slot 3
    else            ws[H1_OFF   + ((size_t)g * 2 + 1) * 4096 + row * 256 + col] = v;  // h1[-1] -> buf 1
  } else if (i < 131072 + N_FLAGS) {
    ((int*)(ws + FLAGS_OFF))[i - 131072] = 0;
  }
}

// ---------------- fragment helpers (verified gfx950 16x16x32 layouts) ----------------
// A/B frag: element j of lane l maps to [m|n = l&15][k = (l>>4)*8 + j]
struct frag2 { short8 h, m; };

// x A-frag: split fp32 into 2 bf16 planes (~2^-18 rel error)
__device__ __forceinline__ frag2 lda_x2(const float* base, int ldk, int kc, int lane) {
  const float* p = base + (size_t)(lane & 15) * ldk + kc * 32 + ((lane >> 4) << 3);
  f32x4 a = *(const f32x4*)p;
  f32x4 b = *(const f32x4*)(p + 4);
  float v[8] = {a[0], a[1], a[2], a[3], b[0], b[1], b[2], b[3]};
  frag2 r;
#pragma unroll
  for (int j = 0; j < 8; j++) {
    float f = v[j];
    ushort_t x = f2bf(f); f -= bf2f(x);
    ushort_t y = f2bf(f);
    r.h[j] = (short)x; r.m[j] = (short)y;
  }
  return r;
}
// 1-plane weight B-frag: W[row + n][kc*32 + quad*8 + j], RNE bf16 (R7-validated numerics)
__device__ __forceinline__ short8 ldw1(const float* base, int ldk, int row, int kc, int lane) {
  const float* p = base + (size_t)(row + (lane & 15)) * ldk + kc * 32 + ((lane >> 4) << 3);
  f32x4 a = *(const f32x4*)p;
  f32x4 b = *(const f32x4*)(p + 4);
  short8 r;
  r[0] = (short)f2bf(a[0]); r[1] = (short)f2bf(a[1]);
  r[2] = (short)f2bf(a[2]); r[3] = (short)f2bf(a[3]);
  r[4] = (short)f2bf(b[0]); r[5] = (short)f2bf(b[1]);
  r[6] = (short)f2bf(b[2]); r[7] = (short)f2bf(b[3]);
  return r;
}
// packed-h A-frag: 4x8B tracked agent-relaxed loads (sc0: bypass L1, hit XCD L2) + decode
__device__ __forceinline__ frag2 ld_packed(const uint_t* p) {
  const u64_t* qp = (const u64_t*)p;
  u64_t d0 = __hip_atomic_load(qp + 0, __ATOMIC_RELAXED, __HIP_MEMORY_SCOPE_AGENT);
  u64_t d1 = __hip_atomic_load(qp + 1, __ATOMIC_RELAXED, __HIP_MEMORY_SCOPE_AGENT);
  u64_t d2 = __hip_atomic_load(qp + 2, __ATOMIC_RELAXED, __HIP_MEMORY_SCOPE_AGENT);
  u64_t d3 = __hip_atomic_load(qp + 3, __ATOMIC_RELAXED, __HIP_MEMORY_SCOPE_AGENT);
  u64_t d[4] = {d0, d1, d2, d3};
  frag2 f;
#pragma unroll
  for (int j = 0; j < 4; j++) {
    uint_t lo = (uint_t)d[j];
    uint_t hi = (uint_t)(d[j] >> 32);
    f.h[2 * j]     = (short)(lo & 0xffffu); f.m[2 * j]     = (short)(lo >> 16);
    f.h[2 * j + 1] = (short)(hi & 0xffffu); f.m[2 * j + 1] = (short)(hi >> 16);
  }
  return f;
}
#define CFENCE() asm volatile("" ::: "memory")

__device__ __forceinline__ f32x4 mfma_(short8 a, short8 b, f32x4 c) {
  return __builtin_amdgcn_mfma_f32_16x16x32_bf16(a, b, c, 0, 0, 0);
}
// Combined wave poll: lanes 0-15 watch sA[lane]>=tA, lanes 16-31 watch sB[lane-16]>=tB,
// lanes 32-63 pass. Single loop, single wait segment. tgt<=0 => pass.
__device__ __forceinline__ int wpoll(const int* sA, int tA, const int* sB, int tB,
                                     int lane, int aborted) {
  if (aborted) return aborted;
  if (tA <= 0 && tB <= 0) return aborted;
  const int li = lane & 15;
  const int sel = (lane >> 4) & 3;
  const int* p = (sel == 1) ? (sB + li) : (sA + li);
  const int tgt = (sel == 0) ? tA : ((sel == 1) ? tB : -2147483647);
  int n = 0;
  for (;;) {
    int v = __hip_atomic_load(p, __ATOMIC_RELAXED, __HIP_MEMORY_SCOPE_AGENT);
    if (__all(tgt <= 0 || v >= tgt)) break;
    if (++n > SPIN_MAX) return 1;
  }
  return 0;
}
__device__ __forceinline__ int get_xcc() {
  int x;
  asm volatile("s_getreg_b32 %0, hwreg(HW_REG_XCC_ID)" : "=s"(x));
  return x & 15;
}
// GRU pointwise, fast transcendentals (R7-validated: contributes to absmax 0.0059)
__device__ __forceinline__ float cellpw_fast(float gr, float gz, float np, float h) {
  float r = __builtin_amdgcn_rcpf(1.0f + __builtin_amdgcn_exp2f(-1.44269504089f * gr));
  float z = __builtin_amdgcn_rcpf(1.0f + __builtin_amdgcn_exp2f(-1.44269504089f * gz));
  float a = np + r * h;
  float n = 1.0f - 2.0f * __builtin_amdgcn_rcpf(1.0f + __builtin_amdgcn_exp2f(2.88539008177f * a));
  return (1.0f - z) * n + z * h;
}

// ---------------- persistent kernel: 128 WGs x 256 thr (1/CU), per-WAVE relay agents --
// bid: g = bid&15, slice = (bid>>4)&3, role = bid>>6. All 8 blocks of group g share
// an XCD (bid = g mod 16 -> bid mod 8 = g mod 8); runtime-checked, fence fallback.
// Wave ws = slice*4+wv owns output cols [ws*16, ws*16+16) x all 3 gates:
// accumulators complete in-wave -> NO LDS reduction, NO __syncthreads in main loop.
__global__ void __launch_bounds__(256, 1)
gru_main(const float* __restrict__ x,
         const float* __restrict__ Wi0, const float* __restrict__ Wh0, const float* __restrict__ Wn0,
         const float* __restrict__ Wi1, const float* __restrict__ Wh1, const float* __restrict__ Wn1,
         const float* __restrict__ state, float* __restrict__ out,
         uint_t* __restrict__ ws, int* __restrict__ unused_flags) {
  __shared__ int s_fast;

  const int tid = (int)threadIdx.x;
  const int lane = tid & 63;
  const int wv = tid >> 6;
  const int bid = (int)blockIdx.x;
  const int g = bid & 15;
  const int slice = (bid >> 4) & 3;
  const int role = bid >> 6;               // 0 = L0 chain, 1 = L1 chain
  const int gb = g * 16;
  const int wslot = slice * 4 + wv;        // 0..15 per role
  const int c0 = wslot * 16;               // this wave's output-col base
  const int q = lane >> 4;
  const int pcol = c0 + (lane & 15);

  uint_t* ring0 = ws + RING0_OFF;
  uint_t* h1b = ws + H1_OFF;
  int* flags = (int*)(ws + FLAGS_OFF);
  int* slots0 = flags + g * 16;
  int* slots1 = flags + 256 + g * 16;
  int* myslot = (role ? slots1 : slots0) + wslot;

  // ---- one-time group XCD-locality check (8 blocks of this group) ----
  if (tid == 0) {
    int myx = get_xcc();
    __hip_atomic_store(&flags[512 + bid], myx, __ATOMIC_RELAXED, __HIP_MEMORY_SCOPE_AGENT);
    __threadfence();
    __hip_atomic_fetch_add(&flags[768 + g * 16], 1, __ATOMIC_RELEASE, __HIP_MEMORY_SCOPE_AGENT);
    int n = 0, ab = 0;
    while (__hip_atomic_load(&flags[768 + g * 16], __ATOMIC_RELAXED,
                             __HIP_MEMORY_SCOPE_AGENT) < 8) {
      if (++n > SPIN_MAX) { ab = 1; break; }
    }
    __threadfence();
    int f = ab ? 0 : 1;
    if (!ab) {
#pragma unroll
      for (int k = 0; k < 8; k++)
        f &= (__hip_atomic_load(&flags[512 + g + 16 * k], __ATOMIC_RELAXED,
                                __HIP_MEMORY_SCOPE_AGENT) == myx);
    }
    s_fast = f;
  }

  // ---- fp32 carry in registers: thread holds rows q*4+r, col pcol ----
  float hcar[4];
  {
    const float* st = state + (size_t)role * B_ * H_;
#pragma unroll
    for (int r = 0; r < 4; r++) hcar[r] = st[(size_t)(gb + q * 4 + r) * H_ + pcol];
  }

  int aborted = 0;
  const f32x4 zz = {0.f, 0.f, 0.f, 0.f};

  if (role == 0) {
    //========== L0 chain: wave computes r,z,n for its 16 cols; 1 wait/step ==========
    // stationary 1-plane weights: 28 short8 = 112 VGPR
    short8 Wr[12], Wz[12], Wn[4];
#pragma unroll
    for (int kc = 0; kc < 4; kc++) Wr[kc] = ldw1(Wi0, I_, c0, kc, lane);
#pragma unroll
    for (int kc = 0; kc < 8; kc++) Wr[4 + kc] = ldw1(Wh0, H_, c0, kc, lane);
#pragma unroll
    for (int kc = 0; kc < 4; kc++) Wz[kc] = ldw1(Wi0, I_, 256 + c0, kc, lane);
#pragma unroll
    for (int kc = 0; kc < 8; kc++) Wz[4 + kc] = ldw1(Wh0, H_, 256 + c0, kc, lane);
#pragma unroll
    for (int kc = 0; kc < 4; kc++) Wn[kc] = ldw1(Wn0, I_, c0, kc, lane);
    __syncthreads();
    const int fast = s_fast;

    for (int t = 0; t < T_; t++) {
      f32x4 ar = zz, az = zz, an = zz;
      // x-part: independent of peers, overlaps their publish latency
      const float* xt = x + ((size_t)t * B_ + gb) * I_;
#pragma unroll
      for (int kc = 0; kc < 4; kc++) {
        frag2 a = lda_x2(xt, I_, kc, lane);
        ar = mfma_(a.h, Wr[kc], ar); ar = mfma_(a.m, Wr[kc], ar);
        az = mfma_(a.h, Wz[kc], az); az = mfma_(a.m, Wz[kc], az);
        an = mfma_(a.h, Wn[kc], an); an = mfma_(a.m, Wn[kc], an);
      }
      // ONE wait: h0[t-1] ready (slots0>=t) + ring WAR vs L1 readers (slots1>=t-3)
      aborted = wpoll(slots0, t, slots1, t - 3, lane, aborted);
      if (!fast) __threadfence();
      CFENCE();
      const uint_t* P = ring0 + ((size_t)g * 4 + ((t + 3) & 3)) * 4096
                        + (size_t)(lane & 15) * 256 + ((lane >> 4) << 3);
#pragma unroll
      for (int kc = 0; kc < 8; kc++) {
        frag2 a = ld_packed(P + kc * 32);
        ar = mfma_(a.h, Wr[4 + kc], ar); ar = mfma_(a.m, Wr[4 + kc], ar);
        az = mfma_(a.h, Wz[4 + kc], az); az = mfma_(a.m, Wz[4 + kc], az);
      }
      // pointwise + publish straight from registers (no LDS, no barrier)
      uint_t* wdst = ring0 + ((size_t)g * 4 + (t & 3)) * 4096;
#pragma unroll
      for (int r = 0; r < 4; r++) {
        float hn = cellpw_fast(ar[r], az[r], an[r], hcar[r]);
        hcar[r] = hn;
        ushort_t hi = f2bf(hn);
        ushort_t mid = f2bf(hn - bf2f(hi));
        wdst[(size_t)(q * 4 + r) * 256 + pcol] = (uint_t)hi | ((uint_t)mid << 16);
      }
      asm volatile("s_waitcnt vmcnt(0)" ::: "memory");  // publish drained to XCD L2
      if (!fast) __threadfence();
      if (lane == 0)
        __hip_atomic_store(myslot, t + 1, __ATOMIC_RELAXED, __HIP_MEMORY_SCOPE_AGENT);
    }
#pragma unroll
    for (int r = 0; r < 4; r++)
      out[(size_t)T_ * B_ * H_ + (size_t)(gb + q * 4 + r) * H_ + pcol] = hcar[r];
  } else {
    //========== L1 chain: ONE combined wait {h0[t], h1[t-1]} then full compute ==========
    // stationary 1-plane weights: 40 short8 = 160 VGPR
    short8 Wr[16], Wz[16], Wn[8];
#pragma unroll
    for (int kc = 0; kc < 8; kc++) Wr[kc] = ldw1(Wi1, H_, c0, kc, lane);       // Q-side
#pragma unroll
    for (int kc = 0; kc < 8; kc++) Wr[8 + kc] = ldw1(Wh1, H_, c0, kc, lane);   // R-side
#pragma unroll
    for (int kc = 0; kc < 8; kc++) Wz[kc] = ldw1(Wi1, H_, 256 + c0, kc, lane);
#pragma unroll
    for (int kc = 0; kc < 8; kc++) Wz[8 + kc] = ldw1(Wh1, H_, 256 + c0, kc, lane);
#pragma unroll
    for (int kc = 0; kc < 8; kc++) Wn[kc] = ldw1(Wn1, H_, c0, kc, lane);
    __syncthreads();
    const int fast = s_fast;

    for (int t = 0; t < T_; t++) {
      // ONE wait: h0[t] (slots0>=t+1) + h1[t-1] ready/WAR (slots1>=t)
      aborted = wpoll(slots0, t + 1, slots1, t, lane, aborted);
      if (!fast) __threadfence();
      CFENCE();
      f32x4 ar = zz, az = zz, an = zz;
      const uint_t* Q = ring0 + ((size_t)g * 4 + (t & 3)) * 4096
                        + (size_t)(lane & 15) * 256 + ((lane >> 4) << 3);
      const uint_t* R = h1b + ((size_t)g * 2 + ((t + 1) & 1)) * 4096
                        + (size_t)(lane & 15) * 256 + ((lane >> 4) << 3);
#pragma unroll
      for (int kc = 0; kc < 8; kc++) {
        frag2 a = ld_packed(Q + kc * 32);
        ar = mfma_(a.h, Wr[kc], ar); ar = mfma_(a.m, Wr[kc], ar);
        az = mfma_(a.h, Wz[kc], az); az = mfma_(a.m, Wz[kc], az);
        an = mfma_(a.h, Wn[kc], an); an = mfma_(a.m, Wn[kc], an);
      }
#pragma unroll
      for (int kc = 0; kc < 8; kc++) {
        frag2 b = ld_packed(R + kc * 32);
        ar = mfma_(b.h, Wr[8 + kc], ar); ar = mfma_(b.m, Wr[8 + kc], ar);
        az = mfma_(b.h, Wz[8 + kc], az); az = mfma_(b.m, Wz[8 + kc], az);
      }
      uint_t* wdst = h1b + ((size_t)g * 2 + (t & 1)) * 4096;
      float hnv[4];
#pragma unroll
      for (int r = 0; r < 4; r++) {
        float hn = cellpw_fast(ar[r], az[r], an[r], hcar[r]);
        hcar[r] = hn; hnv[r] = hn;
        ushort_t hi = f2bf(hn);
        ushort_t mid = f2bf(hn - bf2f(hi));
        wdst[(size_t)(q * 4 + r) * 256 + pcol] = (uint_t)hi | ((uint_t)mid << 16);
      }
      asm volatile("s_waitcnt vmcnt(0)" ::: "memory");
      if (!fast) __threadfence();
      if (lane == 0)
        __hip_atomic_store(myslot, t + 1, __ATOMIC_RELAXED, __HIP_MEMORY_SCOPE_AGENT);
      // out[t] HBM stores AFTER the bump: drain overlaps next step
#pragma unroll
      for (int r = 0; r < 4; r++)
        out[((size_t)t * B_ + gb + q * 4 + r) * H_ + pcol] = hnv[r];
    }
#pragma unroll
    for (int r = 0; r < 4; r++)
      out[(size_t)T_ * B_ * H_ + (size_t)B_ * H_ + (size_t)(gb + q * 4 + r) * H_ + pcol] =
          hcar[r];
  }

  // diagnostic sentinel: spin abort signature
  if (tid == 0 && aborted) out[(size_t)gb * H_] = 4096.0f;
}

extern "C" void kernel_launch(void* const* d_in, const int* in_sizes, int n_in,
                              void* d_out, int out_size, void* d_ws, size_t ws_size,
                              hipStream_t stream) {
  const float* x     = (const float*)d_in[0];
  const float* state = (const float*)d_in[1];
  const float* Wi0   = (const float*)d_in[2];
  const float* Wh0   = (const float*)d_in[3];
  const float* Wn0   = (const float*)d_in[4];
  const float* Wi1   = (const float*)d_in[5];
  const float* Wh1   = (const float*)d_in[6];
  const float* Wn1   = (const float*)d_in[7];
  float* out = (float*)d_out;
  uint_t* ws = (uint_t*)d_ws;

  prep_kernel<<<dim3((131072 + N_FLAGS + 255) / 256), dim3(256), 0, stream>>>(state, ws);

  gru_main<<<dim3(128), dim3(256), 0, stream>>>(
      x, Wi0, Wh0, Wn0, Wi1, Wh1, Wn1, state, out, ws, nullptr);
}

// Round 11
// 5199.511 us; speedup vs baseline: 2.2284x; 1.0328x over previous
//
#include <hip/hip_runtime.h>

// Problem constants
#define T_ 512
#define B_ 256
#define I_ 128
#define H_ 256
#define SPIN_MAX (1 << 18)

typedef unsigned short ushort_t;
typedef unsigned int uint_t;
typedef unsigned long long u64_t;
typedef __attribute__((ext_vector_type(8))) short short8;  // 8 bf16 (4 VGPRs)
typedef __attribute__((ext_vector_type(4))) float f32x4;

// ws layout (u32 units). h stored PACKED: u32 = hi_bf16 | mid_bf16<<16 (2-plane).
// ring0[g][4][16 rows][256 cols]  : h0 ring, 4 deep   -> 16*4*4096 = 262144 u32
// h1buf[g][2][16 rows][256 cols]  : h1 double buffer  -> 16*2*4096 = 131072 u32
#define RING0_OFF 0
#define H1_OFF    262144
#define FLAGS_OFF 393216
// flags (int):
//  [g*16 + ws]       slots0 : wave ws of L0 published h0[t] => t+1
//  [256 + g*16 + ws] slots1 : wave ws of L1 published h1[t] => t+1
//  [512 + bid]       xcd id per block
//  [768 + g*16]      per-group arrival counter
#define N_FLAGS 1024

__device__ __forceinline__ ushort_t f2bf(float f) {  // RNE f32->bf16
  unsigned int u = __float_as_uint(f);
  u += 0x7fffu + ((u >> 16) & 1u);
  return (ushort_t)(u >> 16);
}
__device__ __forceinline__ float bf2f(ushort_t u) {
  return __uint_as_float(((unsigned int)u) << 16);
}

// ---------------- prep: state -> packed planes + flag zeroing ----------------
__global__ void prep_kernel(const float* __restrict__ state, uint_t* __restrict__ ws) {
  int i = blockIdx.x * 256 + threadIdx.x;
  if (i < 131072) {
    int which = i >> 16;          // 0: h0 state, 1: h1 state
    int j = i & 65535;
    int b = j >> 8, col = j & 255;
    int g = b >> 4, row = b & 15;
    float f = state[i];
    ushort_t hi = f2bf(f);
    ushort_t mid = f2bf(f - bf2f(hi));
    uint_t v = (uint_t)hi | ((uint_t)mid << 16);
    if (which == 0) ws[RING0_OFF + ((size_t)g * 4 + 3) * 4096 + row * 256 + col] = v;  // h0[-1] -> slot 3
    else            ws[H1_OFF   + ((size_t)g * 2 + 1) * 4096 + row * 256 + col] = v;  // h1[-1] -> buf 1
  } else if (i < 131072 + N_FLAGS) {
    ((int*)(ws + FLAGS_OFF))[i - 131072] = 0;
  }
}

// ---------------- fragment helpers (verified gfx950 16x16x32 layouts) ----------------
// A/B frag: element j of lane l maps to [m|n = l&15][k = (l>>4)*8 + j]
struct frag2 { short8 h, m; };

// x A-frag: split fp32 into 2 bf16 planes (~2^-18 rel error)
__device__ __forceinline__ frag2 lda_x2(const float* base, int ldk, int kc, int lane) {
  const float* p = base + (size_t)(lane & 15) * ldk + kc * 32 + ((lane >> 4) << 3);
  f32x4 a = *(const f32x4*)p;
  f32x4 b = *(const f32x4*)(p + 4);
  float v[8] = {a[0], a[1], a[2], a[3], b[0], b[1], b[2], b[3]};
  frag2 r;
#pragma unroll
  for (int j = 0; j < 8; j++) {
    float f = v[j];
    ushort_t x = f2bf(f); f -= bf2f(x);
    ushort_t y = f2bf(f);
    r.h[j] = (short)x; r.m[j] = (short)y;
  }
  return r;
}
// 1-plane weight B-frag: W[row + n][kc*32 + quad*8 + j], RNE bf16 (R7-validated numerics)
__device__ __forceinline__ short8 ldw1(const float* base, int ldk, int row, int kc, int lane) {
  const float* p = base + (size_t)(row + (lane & 15)) * ldk + kc * 32 + ((lane >> 4) << 3);
  f32x4 a = *(const f32x4*)p;
  f32x4 b = *(const f32x4*)(p + 4);
  short8 r;
  r[0] = (short)f2bf(a[0]); r[1] = (short)f2bf(a[1]);
  r[2] = (short)f2bf(a[2]); r[3] = (short)f2bf(a[3]);
  r[4] = (short)f2bf(b[0]); r[5] = (short)f2bf(b[1]);
  r[6] = (short)f2bf(b[2]); r[7] = (short)f2bf(b[3]);
  return r;
}
// packed-h A-frag: 4x8B tracked agent-relaxed loads (sc0: bypass L1, hit XCD L2) + decode
__device__ __forceinline__ frag2 ld_packed(const uint_t* p) {
  const u64_t* qp = (const u64_t*)p;
  u64_t d0 = __hip_atomic_load(qp + 0, __ATOMIC_RELAXED, __HIP_MEMORY_SCOPE_AGENT);
  u64_t d1 = __hip_atomic_load(qp + 1, __ATOMIC_RELAXED, __HIP_MEMORY_SCOPE_AGENT);
  u64_t d2 = __hip_atomic_load(qp + 2, __ATOMIC_RELAXED, __HIP_MEMORY_SCOPE_AGENT);
  u64_t d3 = __hip_atomic_load(qp + 3, __ATOMIC_RELAXED, __HIP_MEMORY_SCOPE_AGENT);
  u64_t d[4] = {d0, d1, d2, d3};
  frag2 f;
#pragma unroll
  for (int j = 0; j < 4; j++) {
    uint_t lo = (uint_t)d[j];
    uint_t hi = (uint_t)(d[j] >> 32);
    f.h[2 * j]     = (short)(lo & 0xffffu); f.m[2 * j]     = (short)(lo >> 16);
    f.h[2 * j + 1] = (short)(hi & 0xffffu); f.m[2 * j + 1] = (short)(hi >> 16);
  }
  return f;
}
#define CFENCE() asm volatile("" ::: "memory")

__device__ __forceinline__ f32x4 mfma_(short8 a, short8 b, f32x4 c) {
  return __builtin_amdgcn_mfma_f32_16x16x32_bf16(a, b, c, 0, 0, 0);
}
// Combined wave poll: lanes 0-15 watch sA[lane]>=tA, lanes 16-31 watch sB[lane-16]>=tB,
// lanes 32-63 pass. Burns a short dependent-FMA chain between polls so the waiting
// SIMD registers VALU activity (DPM clock residency).
__device__ __forceinline__ int wpoll(const int* sA, int tA, const int* sB, int tB,
                                     int lane, int aborted) {
  if (aborted) return aborted;
  if (tA <= 0 && tB <= 0) return aborted;
  const int li = lane & 15;
  const int sel = (lane >> 4) & 3;
  const int* p = (sel == 1) ? (sB + li) : (sA + li);
  const int tgt = (sel == 0) ? tA : ((sel == 1) ? tB : -2147483647);
  int n = 0;
  float burn = 1.0001f;
  for (;;) {
    int v = __hip_atomic_load(p, __ATOMIC_RELAXED, __HIP_MEMORY_SCOPE_AGENT);
    if (__all(tgt <= 0 || v >= tgt)) break;
#pragma unroll
    for (int k = 0; k < 16; k++) burn = __builtin_fmaf(burn, 0.999991f, 1e-9f);
    asm volatile("" : "+v"(burn));
    if (++n > SPIN_MAX) { asm volatile("" :: "v"(burn)); return 1; }
  }
  asm volatile("" :: "v"(burn));
  return 0;
}
__device__ __forceinline__ int get_xcc() {
  int x;
  asm volatile("s_getreg_b32 %0, hwreg(HW_REG_XCC_ID)" : "=s"(x));
  return x & 15;
}
// GRU pointwise, fast transcendentals (R7-validated: contributes to absmax 0.0059)
__device__ __forceinline__ float cellpw_fast(float gr, float gz, float np, float h) {
  float r = __builtin_amdgcn_rcpf(1.0f + __builtin_amdgcn_exp2f(-1.44269504089f * gr));
  float z = __builtin_amdgcn_rcpf(1.0f + __builtin_amdgcn_exp2f(-1.44269504089f * gz));
  float a = np + r * h;
  float n = 1.0f - 2.0f * __builtin_amdgcn_rcpf(1.0f + __builtin_amdgcn_exp2f(2.88539008177f * a));
  return (1.0f - z) * n + z * h;
}

// ---------------- persistent kernel: 128 WGs x 512 thr (1/CU) ----------------
// Waves 0-3 : worker, byte-identical protocol to R8 (per-WAVE relay agents, no
//             barriers in the main loop). g = bid&15, slice = (bid>>4)&3, role = bid>>6.
// Waves 4-7 : in-block burners -- dependent-FMA loops keeping this CU's SIMDs busy so
//             the DPM governor holds high sclk (relay path = latency x clock period).
//             Exit when the block's 4 worker waves bump an LDS done counter (bounded).
__global__ void __launch_bounds__(512, 2)
gru_main(const float* __restrict__ x,
         const float* __restrict__ Wi0, const float* __restrict__ Wh0, const float* __restrict__ Wn0,
         const float* __restrict__ Wi1, const float* __restrict__ Wh1, const float* __restrict__ Wn1,
         const float* __restrict__ state, float* __restrict__ out,
         uint_t* __restrict__ ws, int* __restrict__ unused_flags) {
  __shared__ int s_fast;
  __shared__ int s_done;

  const int tid = (int)threadIdx.x;
  const int lane = tid & 63;
  const int wv8 = tid >> 6;                // wave 0..7
  const int wv = wv8 & 3;                  // worker wave id 0..3
  const int bid = (int)blockIdx.x;
  int* flags = (int*)(ws + FLAGS_OFF);

  const int g = bid & 15;
  const int slice = (bid >> 4) & 3;
  const int role = bid >> 6;               // 0 = L0 chain, 1 = L1 chain
  const int gb = g * 16;
  const int wslot = slice * 4 + wv;        // 0..15 per role
  const int c0 = wslot * 16;               // this wave's output-col base
  const int q = lane >> 4;
  const int pcol = c0 + (lane & 15);

  uint_t* ring0 = ws + RING0_OFF;
  uint_t* h1b = ws + H1_OFF;
  int* slots0 = flags + g * 16;
  int* slots1 = flags + 256 + g * 16;
  int* myslot = (role ? slots1 : slots0) + wslot;

  // ---- one-time group XCD-locality check (8 blocks of this group) ----
  if (tid == 0) {
    s_done = 0;
    int myx = get_xcc();
    __hip_atomic_store(&flags[512 + bid], myx, __ATOMIC_RELAXED, __HIP_MEMORY_SCOPE_AGENT);
    __threadfence();
    __hip_atomic_fetch_add(&flags[768 + g * 16], 1, __ATOMIC_RELEASE, __HIP_MEMORY_SCOPE_AGENT);
    int n = 0, ab = 0;
    while (__hip_atomic_load(&flags[768 + g * 16], __ATOMIC_RELAXED,
                             __HIP_MEMORY_SCOPE_AGENT) < 8) {
      if (++n > SPIN_MAX) { ab = 1; break; }
    }
    __threadfence();
    int f = ab ? 0 : 1;
    if (!ab) {
#pragma unroll
      for (int k = 0; k < 8; k++)
        f &= (__hip_atomic_load(&flags[512 + g + 16 * k], __ATOMIC_RELAXED,
                                __HIP_MEMORY_SCOPE_AGENT) == myx);
    }
    s_fast = f;
  }

  // ---- worker waves: stationary 1-plane weights + fp32 carry in registers ----
  short8 Wr[16], Wz[16], Wn[8];
  float hcar[4];
  if (wv8 < 4) {
    if (role == 0) {
#pragma unroll
      for (int kc = 0; kc < 4; kc++) Wr[kc] = ldw1(Wi0, I_, c0, kc, lane);
#pragma unroll
      for (int kc = 0; kc < 8; kc++) Wr[4 + kc] = ldw1(Wh0, H_, c0, kc, lane);
#pragma unroll
      for (int kc = 0; kc < 4; kc++) Wz[kc] = ldw1(Wi0, I_, 256 + c0, kc, lane);
#pragma unroll
      for (int kc = 0; kc < 8; kc++) Wz[4 + kc] = ldw1(Wh0, H_, 256 + c0, kc, lane);
#pragma unroll
      for (int kc = 0; kc < 4; kc++) Wn[kc] = ldw1(Wn0, I_, c0, kc, lane);
    } else {
#pragma unroll
      for (int kc = 0; kc < 8; kc++) Wr[kc] = ldw1(Wi1, H_, c0, kc, lane);       // Q-side
#pragma unroll
      for (int kc = 0; kc < 8; kc++) Wr[8 + kc] = ldw1(Wh1, H_, c0, kc, lane);   // R-side
#pragma unroll
      for (int kc = 0; kc < 8; kc++) Wz[kc] = ldw1(Wi1, H_, c0 + 256, kc, lane);
#pragma unroll
      for (int kc = 0; kc < 8; kc++) Wz[8 + kc] = ldw1(Wh1, H_, c0 + 256, kc, lane);
#pragma unroll
      for (int kc = 0; kc < 8; kc++) Wn[kc] = ldw1(Wn1, H_, c0, kc, lane);
    }
    const float* st = state + (size_t)role * B_ * H_;
#pragma unroll
    for (int r = 0; r < 4; r++) hcar[r] = st[(size_t)(gb + q * 4 + r) * H_ + pcol];
  }

  __syncthreads();  // the ONLY barrier: everyone sees s_fast / s_done init
  const int fast = s_fast;

  //=================== burner waves: keep this CU's clock up ===================
  if (wv8 >= 4) {
    float a = 1.0001f;
    const float bb = 0.999991f;
    int it = 0;
    for (;;) {
#pragma unroll
      for (int k = 0; k < 128; k++) a = __builtin_fmaf(a, bb, 1e-9f);  // dependent chain
      asm volatile("" : "+v"(a));
      if (__hip_atomic_load(&s_done, __ATOMIC_RELAXED, __HIP_MEMORY_SCOPE_WORKGROUP) >= 4)
        break;
      if (++it > (1 << 14)) break;  // bounded fallback ~3.5 ms @2.4 GHz
    }
    asm volatile("" :: "v"(a));
    return;
  }

  //=================== worker waves (R8 protocol, unchanged) ===================
  int aborted = 0;
  const f32x4 zz = {0.f, 0.f, 0.f, 0.f};

  if (role == 0) {
    //========== L0 chain: wave computes r,z,n for its 16 cols; 1 wait/step ==========
    for (int t = 0; t < T_; t++) {
      f32x4 ar = zz, az = zz, an = zz;
      // x-part: independent of peers, overlaps their publish latency
      const float* xt = x + ((size_t)t * B_ + gb) * I_;
#pragma unroll
      for (int kc = 0; kc < 4; kc++) {
        frag2 a = lda_x2(xt, I_, kc, lane);
        ar = mfma_(a.h, Wr[kc], ar); ar = mfma_(a.m, Wr[kc], ar);
        az = mfma_(a.h, Wz[kc], az); az = mfma_(a.m, Wz[kc], az);
        an = mfma_(a.h, Wn[kc], an); an = mfma_(a.m, Wn[kc], an);
      }
      // ONE wait: h0[t-1] ready (slots0>=t) + ring WAR vs L1 readers (slots1>=t-3)
      aborted = wpoll(slots0, t, slots1, t - 3, lane, aborted);
      if (!fast) __threadfence();
      CFENCE();
      const uint_t* P = ring0 + ((size_t)g * 4 + ((t + 3) & 3)) * 4096
                        + (size_t)(lane & 15) * 256 + ((lane >> 4) << 3);
#pragma unroll
      for (int kc = 0; kc < 8; kc++) {
        frag2 a = ld_packed(P + kc * 32);
        ar = mfma_(a.h, Wr[4 + kc], ar); ar = mfma_(a.m, Wr[4 + kc], ar);
        az = mfma_(a.h, Wz[4 + kc], az); az = mfma_(a.m, Wz[4 + kc], az);
      }
      // pointwise + publish straight from registers (no LDS, no barrier)
      uint_t* wdst = ring0 + ((size_t)g * 4 + (t & 3)) * 4096;
#pragma unroll
      for (int r = 0; r < 4; r++) {
        float hn = cellpw_fast(ar[r], az[r], an[r], hcar[r]);
        hcar[r] = hn;
        ushort_t hi = f2bf(hn);
        ushort_t mid = f2bf(hn - bf2f(hi));
        wdst[(size_t)(q * 4 + r) * 256 + pcol] = (uint_t)hi | ((uint_t)mid << 16);
      }
      asm volatile("s_waitcnt vmcnt(0)" ::: "memory");  // publish drained to XCD L2
      if (!fast) __threadfence();
      if (lane == 0)
        __hip_atomic_store(myslot, t + 1, __ATOMIC_RELAXED, __HIP_MEMORY_SCOPE_AGENT);
    }
#pragma unroll
    for (int r = 0; r < 4; r++)
      out[(size_t)T_ * B_ * H_ + (size_t)(gb + q * 4 + r) * H_ + pcol] = hcar[r];
  } else {
    //========== L1 chain: ONE combined wait {h0[t], h1[t-1]} then full compute ==========
    for (int t = 0; t < T_; t++) {
      // ONE wait: h0[t] (slots0>=t+1) + h1[t-1] ready/WAR (slots1>=t)
      aborted = wpoll(slots0, t + 1, slots1, t, lane, aborted);
      if (!fast) __threadfence();
      CFENCE();
      f32x4 ar = zz, az = zz, an = zz;
      const uint_t* Q = ring0 + ((size_t)g * 4 + (t & 3)) * 4096
                        + (size_t)(lane & 15) * 256 + ((lane >> 4) << 3);
      const uint_t* R = h1b + ((size_t)g * 2 + ((t + 1) & 1)) * 4096
                        + (size_t)(lane & 15) * 256 + ((lane >> 4) << 3);
#pragma unroll
      for (int kc = 0; kc < 8; kc++) {
        frag2 a = ld_packed(Q + kc * 32);
        ar = mfma_(a.h, Wr[kc], ar); ar = mfma_(a.m, Wr[kc], ar);
        az = mfma_(a.h, Wz[kc], az); az = mfma_(a.m, Wz[kc], az);
        an = mfma_(a.h, Wn[kc], an); an = mfma_(a.m, Wn[kc], an);
      }
#pragma unroll
      for (int kc = 0; kc < 8; kc++) {
        frag2 b = ld_packed(R + kc * 32);
        ar = mfma_(b.h, Wr[8 + kc], ar); ar = mfma_(b.m, Wr[8 + kc], ar);
        az = mfma_(b.h, Wz[8 + kc], az); az = mfma_(b.m, Wz[8 + kc], az);
      }
      uint_t* wdst = h1b + ((size_t)g * 2 + (t & 1)) * 4096;
      float hnv[4];
#pragma unroll
      for (int r = 0; r < 4; r++) {
        float hn = cellpw_fast(ar[r], az[r], an[r], hcar[r]);
        hcar[r] = hn; hnv[r] = hn;
        ushort_t hi = f2bf(hn);
        ushort_t mid = f2bf(hn - bf2f(hi));
        wdst[(size_t)(q * 4 + r) * 256 + pcol] = (uint_t)hi | ((uint_t)mid << 16);
      }
      asm volatile("s_waitcnt vmcnt(0)" ::: "memory");
      if (!fast) __threadfence();
      if (lane == 0)
        __hip_atomic_store(myslot, t + 1, __ATOMIC_RELAXED, __HIP_MEMORY_SCOPE_AGENT);
      // out[t] HBM stores AFTER the bump: drain overlaps next step
#pragma unroll
      for (int r = 0; r < 4; r++)
        out[((size_t)t * B_ + gb + q * 4 + r) * H_ + pcol] = hnv[r];
    }
#pragma unroll
    for (int r = 0; r < 4; r++)
      out[(size_t)T_ * B_ * H_ + (size_t)B_ * H_ + (size_t)(gb + q * 4 + r) * H_ + pcol] =
          hcar[r];
  }

  // this worker wave done -> burner waves may exit
  if (lane == 0)
    __hip_atomic_fetch_add(&s_done, 1, __ATOMIC_RELAXED, __HIP_MEMORY_SCOPE_WORKGROUP);

  // diagnostic sentinel: spin abort signature
  if (tid == 0 && aborted) out[(size_t)gb * H_] = 4096.0f;
}

extern "C" void kernel_launch(void* const* d_in, const int* in_sizes, int n_in,
                              void* d_out, int out_size, void* d_ws, size_t ws_size,
                              hipStream_t stream) {
  const float* x     = (const float*)d_in[0];
  const float* state = (const float*)d_in[1];
  const float* Wi0   = (const float*)d_in[2];
  const float* Wh0   = (const float*)d_in[3];
  const float* Wn0   = (const float*)d_in[4];
  const float* Wi1   = (const float*)d_in[5];
  const float* Wh1   = (const float*)d_in[6];
  const float* Wn1   = (const float*)d_in[7];
  float* out = (float*)d_out;
  uint_t* ws = (uint_t*)d_ws;

  prep_kernel<<<dim3((131072 + N_FLAGS + 255) / 256), dim3(256), 0, stream>>>(state, ws);

  gru_main<<<dim3(128), dim3(512), 0, stream>>>(
      x, Wi0, Wh0, Wn0, Wi1, Wh1, Wn1, state, out, ws, nullptr);
}

// Round 12
// 3076.296 us; speedup vs baseline: 3.7665x; 1.6902x over previous
//
#include <hip/hip_runtime.h>

// Problem constants
#define T_ 512
#define B_ 256
#define I_ 128
#define H_ 256
#define SPIN_MAX (1 << 18)

typedef unsigned short ushort_t;
typedef unsigned int uint_t;
typedef unsigned long long u64_t;
typedef __attribute__((ext_vector_type(8))) short short8;  // 8 bf16 (4 VGPRs)
typedef __attribute__((ext_vector_type(4))) float f32x4;

// ---- workspace layout (u32 units) ----
// xg  [16 g][4 slot][16 row][768] f32 : L0 x-part gate partials (r|z|n segments)
// h0r [16][4][16][256] u32           : h0 packed hi|mid bf16 planes
// qa  [16][4][16][512] f32           : L1 Q-side partials (r|z)
// qb  [16][4][16][256] f32           : L1 n1 partials
#define XG_OFF   0
#define H0R_OFF  786432
#define QA_OFF   1048576
#define QB_OFF   1572864
#define FL_OFF   1835008
#define N_FLAGS  2048
// flags: per group stride 32: [0..3]=sX[wv] [8]=sH0 [12..15]=sQa[wv] [16..19]=sQb[wv] [24]=sR
//        [1024+bid]=xcd  [1536+g*16]=arrival counter (target 5)

__device__ __forceinline__ ushort_t f2bf(float f) {  // RNE f32->bf16
  unsigned int u = __float_as_uint(f);
  u += 0x7fffu + ((u >> 16) & 1u);
  return (ushort_t)(u >> 16);
}
__device__ __forceinline__ float bf2f(ushort_t u) {
  return __uint_as_float(((unsigned int)u) << 16);
}

// ---------------- prep: flag zeroing only (state goes straight to LDS) ------------
__global__ void prep_kernel(uint_t* __restrict__ ws) {
  int i = blockIdx.x * 256 + threadIdx.x;
  if (i < N_FLAGS) ((int*)(ws + FL_OFF))[i] = 0;
}

// ---------------- fragment helpers (verified gfx950 16x16x32 layouts) ----------------
struct frag2 { short8 h, m; };

// x A-frag: split fp32 into 2 bf16 planes
__device__ __forceinline__ frag2 lda_x2(const float* base, int ldk, int kc, int lane) {
  const float* p = base + (size_t)(lane & 15) * ldk + kc * 32 + ((lane >> 4) << 3);
  f32x4 a = *(const f32x4*)p;
  f32x4 b = *(const f32x4*)(p + 4);
  float v[8] = {a[0], a[1], a[2], a[3], b[0], b[1], b[2], b[3]};
  frag2 r;
#pragma unroll
  for (int j = 0; j < 8; j++) {
    float f = v[j];
    ushort_t xx = f2bf(f); f -= bf2f(xx);
    ushort_t y = f2bf(f);
    r.h[j] = (short)xx; r.m[j] = (short)y;
  }
  return r;
}
// 1-plane weight B-frag (R7-validated numerics)
__device__ __forceinline__ short8 ldw1(const float* base, int ldk, int row, int kc, int lane) {
  const float* p = base + (size_t)(row + (lane & 15)) * ldk + kc * 32 + ((lane >> 4) << 3);
  f32x4 a = *(const f32x4*)p;
  f32x4 b = *(const f32x4*)(p + 4);
  short8 r;
  r[0] = (short)f2bf(a[0]); r[1] = (short)f2bf(a[1]);
  r[2] = (short)f2bf(a[2]); r[3] = (short)f2bf(a[3]);
  r[4] = (short)f2bf(b[0]); r[5] = (short)f2bf(b[1]);
  r[6] = (short)f2bf(b[2]); r[7] = (short)f2bf(b[3]);
  return r;
}
// packed-h A-frag from L2 ring: 4x8B tracked agent-relaxed loads + decode
__device__ __forceinline__ frag2 ld_packed(const uint_t* p) {
  const u64_t* qp = (const u64_t*)p;
  u64_t d0 = __hip_atomic_load(qp + 0, __ATOMIC_RELAXED, __HIP_MEMORY_SCOPE_AGENT);
  u64_t d1 = __hip_atomic_load(qp + 1, __ATOMIC_RELAXED, __HIP_MEMORY_SCOPE_AGENT);
  u64_t d2 = __hip_atomic_load(qp + 2, __ATOMIC_RELAXED, __HIP_MEMORY_SCOPE_AGENT);
  u64_t d3 = __hip_atomic_load(qp + 3, __ATOMIC_RELAXED, __HIP_MEMORY_SCOPE_AGENT);
  u64_t d[4] = {d0, d1, d2, d3};
  frag2 f;
#pragma unroll
  for (int j = 0; j < 4; j++) {
    uint_t lo = (uint_t)d[j];
    uint_t hi = (uint_t)(d[j] >> 32);
    f.h[2 * j]     = (short)(lo & 0xffffu); f.m[2 * j]     = (short)(lo >> 16);
    f.h[2 * j + 1] = (short)(hi & 0xffffu); f.m[2 * j + 1] = (short)(hi >> 16);
  }
  return f;
}
// f32 load via agent-relaxed atomic (L1-bypass, compiler-tracked)
__device__ __forceinline__ float ldf32(const uint_t* p) {
  uint_t v = __hip_atomic_load(p, __ATOMIC_RELAXED, __HIP_MEMORY_SCOPE_AGENT);
  return __uint_as_float(v);
}
#define CFENCE() asm volatile("" ::: "memory")

__device__ __forceinline__ f32x4 mfma_(short8 a, short8 b, f32x4 c) {
  return __builtin_amdgcn_mfma_f32_16x16x32_bf16(a, b, c, 0, 0, 0);
}
// per-lane-mapped poll: lane spins (act && tgt>0) until *p >= tgt; wave exits on __all
__device__ __forceinline__ int lpoll(const int* p, int tgt, int act, int aborted) {
  if (aborted) return aborted;
  int n = 0;
  for (;;) {
    int ok = 1;
    if (act && tgt > 0)
      ok = (__hip_atomic_load(p, __ATOMIC_RELAXED, __HIP_MEMORY_SCOPE_AGENT) >= tgt);
    if (__all(ok)) return 0;
    if (++n > SPIN_MAX) return 1;
  }
}
// single-shot check (prefetch of next step's condition, off the critical path)
__device__ __forceinline__ int lcheck(const int* p, int tgt, int act) {
  int ok = 1;
  if (act && tgt > 0)
    ok = (__hip_atomic_load(p, __ATOMIC_RELAXED, __HIP_MEMORY_SCOPE_AGENT) >= tgt);
  return __all(ok);
}
__device__ __forceinline__ void stflag(int* p, int v) {
  __hip_atomic_store(p, v, __ATOMIC_RELAXED, __HIP_MEMORY_SCOPE_AGENT);
}
__device__ __forceinline__ int get_xcc() {
  int x;
  asm volatile("s_getreg_b32 %0, hwreg(HW_REG_XCC_ID)" : "=s"(x));
  return x & 15;
}
// GRU pointwise, fast transcendentals (R7-validated)
__device__ __forceinline__ float cellpw_fast(float gr, float gz, float np, float h) {
  float r = __builtin_amdgcn_rcpf(1.0f + __builtin_amdgcn_exp2f(-1.44269504089f * gr));
  float z = __builtin_amdgcn_rcpf(1.0f + __builtin_amdgcn_exp2f(-1.44269504089f * gz));
  float a = np + r * h;
  float n = 1.0f - 2.0f * __builtin_amdgcn_rcpf(1.0f + __builtin_amdgcn_exp2f(2.88539008177f * a));
  return (1.0f - z) * n + z * h;
}

// -------- persistent kernel: 80 WGs x 256 thr (5 CUs per group) --------------------
// role = bid>>4: 0=X (L0 x-part server), 1=H0 (h0 recurrence, INTRA-CU),
//                2=Qa (L1 r,z Q-side), 3=Qb (L1 n1 Q-side), 4=R (h1 recurrence, INTRA-CU)
// All 5 blocks of group g have bid = role*16+g == g (mod 8) -> one XCD (runtime-checked).
// The ONLY serial chains (h0, h1) relay through LDS + __syncthreads; every cross-CU
// link is feed-forward with a depth-4 ring -> polls pre-satisfied in steady state.
__global__ void __launch_bounds__(256, 1)
gru_main(const float* __restrict__ x,
         const float* __restrict__ Wi0, const float* __restrict__ Wh0, const float* __restrict__ Wn0,
         const float* __restrict__ Wi1, const float* __restrict__ Wh1, const float* __restrict__ Wn1,
         const float* __restrict__ state, float* __restrict__ out,
         uint_t* __restrict__ ws, int* __restrict__ unused_flags) {
  __shared__ ushort_t hp[2][2][16][264];  // [parity][plane][row][col] packed h planes
  __shared__ float hf[16][264];           // fp32 h carry
  __shared__ int s_fast;

  const int tid = (int)threadIdx.x;
  const int lane = tid & 63;
  const int wv = tid >> 6;
  const int bid = (int)blockIdx.x;
  const int g = bid & 15;
  const int role = bid >> 4;
  const int gb = g * 16;
  const int c0 = wv * 64;                 // this wave's 64 output cols (4 tiles)
  const int arow = lane & 15;
  const int acol = (lane >> 4) << 3;
  const int q = lane >> 4;

  int* flags = (int*)(ws + FL_OFF);
  int* fg = flags + g * 32;
  uint_t* xgp = ws + XG_OFF + (size_t)g * 49152;
  uint_t* h0r = ws + H0R_OFF + (size_t)g * 16384;
  uint_t* qap = ws + QA_OFF + (size_t)g * 32768;
  uint_t* qbp = ws + QB_OFF + (size_t)g * 16384;

  // ---- one-time group XCD-locality check (5 blocks) ----
  if (tid == 0) {
    int myx = get_xcc();
    __hip_atomic_store(&flags[1024 + bid], myx, __ATOMIC_RELAXED, __HIP_MEMORY_SCOPE_AGENT);
    __threadfence();
    __hip_atomic_fetch_add(&flags[1536 + g * 16], 1, __ATOMIC_RELEASE, __HIP_MEMORY_SCOPE_AGENT);
    int n = 0, ab = 0;
    while (__hip_atomic_load(&flags[1536 + g * 16], __ATOMIC_RELAXED,
                             __HIP_MEMORY_SCOPE_AGENT) < 5) {
      if (++n > SPIN_MAX) { ab = 1; break; }
    }
    __threadfence();
    int f = ab ? 0 : 1;
    if (!ab) {
#pragma unroll
      for (int r = 0; r < 5; r++)
        f &= (__hip_atomic_load(&flags[1024 + r * 16 + g], __ATOMIC_RELAXED,
                                __HIP_MEMORY_SCOPE_AGENT) == myx);
    }
    s_fast = f;
  }

  // ---- recurrence CUs: init h[-1] into LDS (parity 1) ----
  if (role == 1 || role == 4) {
    const float* st = state + (role == 4 ? (size_t)B_ * H_ : 0);
#pragma unroll
    for (int j = 0; j < 4; j++)
#pragma unroll
      for (int e = 0; e < 4; e++) {
        int row = q * 4 + e, col = c0 + 16 * j + (lane & 15);
        float f = st[(size_t)(gb + row) * H_ + col];
        hf[row][col] = f;
        ushort_t hi = f2bf(f), mid = f2bf(f - bf2f(hi));
        hp[1][0][row][col] = hi;
        hp[1][1][row][col] = mid;
      }
  }
  __syncthreads();
  const int fast = s_fast;
  int aborted = 0, ready = 0;
  const f32x4 zz = {0.f, 0.f, 0.f, 0.f};

  if (role == 0) {
    //=========== X: xg[t] = x[t] @ {Wi0 r,z ; Wn0} -- no recurrence, runs ahead ========
    short8 Wxr[4][4], Wxz[4][4], Wxn[4][4];
#pragma unroll
    for (int j = 0; j < 4; j++)
#pragma unroll
      for (int kc = 0; kc < 4; kc++) {
        Wxr[j][kc] = ldw1(Wi0, I_, c0 + 16 * j, kc, lane);
        Wxz[j][kc] = ldw1(Wi0, I_, 256 + c0 + 16 * j, kc, lane);
        Wxn[j][kc] = ldw1(Wn0, I_, c0 + 16 * j, kc, lane);
      }
    const int* wp = fg + 8;  // sH0 (WAR: ring depth 4)
    for (int t = 0; t < T_; t++) {
      if (!ready) aborted = lpoll(wp, t - 3, lane == 0, aborted);
      CFENCE();
      f32x4 ar[4] = {zz, zz, zz, zz}, az[4] = {zz, zz, zz, zz}, an[4] = {zz, zz, zz, zz};
      const float* xt = x + ((size_t)t * B_ + gb) * I_;
#pragma unroll
      for (int kc = 0; kc < 4; kc++) {
        frag2 a = lda_x2(xt, I_, kc, lane);
#pragma unroll
        for (int j = 0; j < 4; j++) {
          ar[j] = mfma_(a.h, Wxr[j][kc], ar[j]); ar[j] = mfma_(a.m, Wxr[j][kc], ar[j]);
          az[j] = mfma_(a.h, Wxz[j][kc], az[j]); az[j] = mfma_(a.m, Wxz[j][kc], az[j]);
          an[j] = mfma_(a.h, Wxn[j][kc], an[j]); an[j] = mfma_(a.m, Wxn[j][kc], an[j]);
        }
      }
      float* xs = (float*)(xgp + (size_t)(t & 3) * 12288);
#pragma unroll
      for (int j = 0; j < 4; j++)
#pragma unroll
        for (int e = 0; e < 4; e++) {
          int row = q * 4 + e, col = c0 + 16 * j + (lane & 15);
          xs[row * 768 + col] = ar[j][e];
          xs[row * 768 + 256 + col] = az[j][e];
          xs[row * 768 + 512 + col] = an[j][e];
        }
      asm volatile("s_waitcnt vmcnt(0)" ::: "memory");
      if (!fast) __threadfence();
      if (lane == 0) stflag(fg + wv, t + 1);
      ready = fast ? lcheck(wp, t - 2, lane == 0) : 0;
    }
  } else if (role == 1) {
    //=========== H0: h0 recurrence, INTRA-CU (LDS + one barrier per step) =============
    short8 Whr[4][8], Whz[4][8];
#pragma unroll
    for (int j = 0; j < 4; j++)
#pragma unroll
      for (int kc = 0; kc < 8; kc++) {
        Whr[j][kc] = ldw1(Wh0, H_, c0 + 16 * j, kc, lane);
        Whz[j][kc] = ldw1(Wh0, H_, 256 + c0 + 16 * j, kc, lane);
      }
    const int hact = lane < 12;  // 0-3: sX(t+1); 4-7: sQa WAR(t-3); 8-11: sQb WAR(t-3)
    const int* hpn = fg + ((lane < 4) ? lane : (lane < 8 ? 12 + (lane - 4) : 16 + (lane - 8)));
    for (int t = 0; t < T_; t++) {
      if (!ready) aborted = lpoll(hpn, (lane < 4) ? t + 1 : t - 3, hact, aborted);
      if (!fast) __threadfence();
      CFENCE();
      const uint_t* xs = xgp + (size_t)(t & 3) * 12288;
      float xr[4][4], xz[4][4], xn[4][4];
#pragma unroll
      for (int j = 0; j < 4; j++)
#pragma unroll
        for (int e = 0; e < 4; e++) {
          int row = q * 4 + e, col = c0 + 16 * j + (lane & 15);
          xr[j][e] = ldf32(xs + row * 768 + col);
          xz[j][e] = ldf32(xs + row * 768 + 256 + col);
          xn[j][e] = ldf32(xs + row * 768 + 512 + col);
        }
      const int par = (t + 1) & 1;
      f32x4 accr[4] = {zz, zz, zz, zz}, accz[4] = {zz, zz, zz, zz};
#pragma unroll
      for (int kc = 0; kc < 8; kc++) {
        short8 ah = *(const short8*)&hp[par][0][arow][kc * 32 + acol];
        short8 am = *(const short8*)&hp[par][1][arow][kc * 32 + acol];
#pragma unroll
        for (int j = 0; j < 4; j++) {
          accr[j] = mfma_(ah, Whr[j][kc], accr[j]); accr[j] = mfma_(am, Whr[j][kc], accr[j]);
          accz[j] = mfma_(ah, Whz[j][kc], accz[j]); accz[j] = mfma_(am, Whz[j][kc], accz[j]);
        }
      }
      uint_t* hdst = h0r + (size_t)(t & 3) * 4096;
#pragma unroll
      for (int j = 0; j < 4; j++)
#pragma unroll
        for (int e = 0; e < 4; e++) {
          int row = q * 4 + e, col = c0 + 16 * j + (lane & 15);
          float gr = accr[j][e] + xr[j][e];
          float gz = accz[j][e] + xz[j][e];
          float h = hf[row][col];
          float hn = cellpw_fast(gr, gz, xn[j][e], h);
          hf[row][col] = hn;
          ushort_t hi = f2bf(hn), mid = f2bf(hn - bf2f(hi));
          hp[t & 1][0][row][col] = hi;
          hp[t & 1][1][row][col] = mid;
          hdst[row * 256 + col] = (uint_t)hi | ((uint_t)mid << 16);
        }
      __syncthreads();  // drains publishes (vmcnt) + orders LDS for next step
      if (tid == 0) { if (!fast) __threadfence(); stflag(fg + 8, t + 1); }
      ready = fast ? lcheck(hpn, (lane < 4) ? t + 2 : t - 2, hact) : 0;
    }
#pragma unroll
    for (int j = 0; j < 4; j++)
#pragma unroll
      for (int e = 0; e < 4; e++) {
        int row = q * 4 + e, col = c0 + 16 * j + (lane & 15);
        out[(size_t)T_ * B_ * H_ + (size_t)(gb + row) * H_ + col] = hf[row][col];
      }
  } else if (role == 2 || role == 3) {
    //=========== Qa/Qb: L1 Q-side partials from h0[t] -- pipelined, no recurrence =====
    const int nt = (role == 2) ? 8 : 4;  // Qa: 4 r-tiles + 4 z-tiles; Qb: 4 n-tiles
    short8 Wq[8][8];
#pragma unroll
    for (int kc = 0; kc < 8; kc++) {
      if (role == 2) {
#pragma unroll
        for (int j = 0; j < 4; j++) {
          Wq[j][kc] = ldw1(Wi1, H_, c0 + 16 * j, kc, lane);
          Wq[4 + j][kc] = ldw1(Wi1, H_, 256 + c0 + 16 * j, kc, lane);
        }
      } else {
#pragma unroll
        for (int j = 0; j < 4; j++) Wq[j][kc] = ldw1(Wn1, H_, c0 + 16 * j, kc, lane);
      }
    }
    const int qact = lane < 2;  // lane0: sH0 >= t+1 ; lane1: sR WAR >= t-3
    const int* qpn = fg + ((lane == 0) ? 8 : 24);
    int* myslot = fg + ((role == 2) ? 12 : 16) + wv;
    for (int t = 0; t < T_; t++) {
      if (!ready) aborted = lpoll(qpn, (lane == 0) ? t + 1 : t - 3, qact, aborted);
      if (!fast) __threadfence();
      CFENCE();
      frag2 A[8];
      const uint_t* src = h0r + (size_t)(t & 3) * 4096 + (size_t)arow * 256 + acol;
#pragma unroll
      for (int kc = 0; kc < 8; kc++) A[kc] = ld_packed(src + kc * 32);
      f32x4 acc[8] = {zz, zz, zz, zz, zz, zz, zz, zz};
#pragma unroll
      for (int kc = 0; kc < 8; kc++) {
#pragma unroll
        for (int j = 0; j < 8; j++) {
          if (j < nt) {
            acc[j] = mfma_(A[kc].h, Wq[j][kc], acc[j]);
            acc[j] = mfma_(A[kc].m, Wq[j][kc], acc[j]);
          }
        }
      }
      if (role == 2) {
        float* qd = (float*)(qap + (size_t)(t & 3) * 8192);
#pragma unroll
        for (int j = 0; j < 4; j++)
#pragma unroll
          for (int e = 0; e < 4; e++) {
            int row = q * 4 + e, col = c0 + 16 * j + (lane & 15);
            qd[row * 512 + col] = acc[j][e];
            qd[row * 512 + 256 + col] = acc[4 + j][e];
          }
      } else {
        float* qd = (float*)(qbp + (size_t)(t & 3) * 4096);
#pragma unroll
        for (int j = 0; j < 4; j++)
#pragma unroll
          for (int e = 0; e < 4; e++) {
            int row = q * 4 + e, col = c0 + 16 * j + (lane & 15);
            qd[row * 256 + col] = acc[j][e];
          }
      }
      asm volatile("s_waitcnt vmcnt(0)" ::: "memory");
      if (!fast) __threadfence();
      if (lane == 0) stflag(myslot, t + 1);
      ready = fast ? lcheck(qpn, (lane == 0) ? t + 2 : t - 2, qact) : 0;
    }
  } else {
    //=========== R: h1 recurrence, INTRA-CU; consumes pipelined Q partials ============
    short8 Wvr[4][8], Wvz[4][8];
#pragma unroll
    for (int j = 0; j < 4; j++)
#pragma unroll
      for (int kc = 0; kc < 8; kc++) {
        Wvr[j][kc] = ldw1(Wh1, H_, c0 + 16 * j, kc, lane);
        Wvz[j][kc] = ldw1(Wh1, H_, 256 + c0 + 16 * j, kc, lane);
      }
    const int ract = lane < 8;  // 0-3: sQa >= t+1 ; 4-7: sQb >= t+1
    const int* rpn = fg + ((lane < 4) ? 12 + lane : 16 + (lane - 4));
    float hnv[4][4];
    for (int t = 0; t < T_; t++) {
      if (!ready) aborted = lpoll(rpn, t + 1, ract, aborted);
      if (!fast) __threadfence();
      CFENCE();
      const uint_t* qas = qap + (size_t)(t & 3) * 8192;
      const uint_t* qbs = qbp + (size_t)(t & 3) * 4096;
      float qr[4][4], qz[4][4], qn[4][4];
#pragma unroll
      for (int j = 0; j < 4; j++)
#pragma unroll
        for (int e = 0; e < 4; e++) {
          int row = q * 4 + e, col = c0 + 16 * j + (lane & 15);
          qr[j][e] = ldf32(qas + row * 512 + col);
          qz[j][e] = ldf32(qas + row * 512 + 256 + col);
          qn[j][e] = ldf32(qbs + row * 256 + col);
        }
      const int par = (t + 1) & 1;
      f32x4 accr[4] = {zz, zz, zz, zz}, accz[4] = {zz, zz, zz, zz};
#pragma unroll
      for (int kc = 0; kc < 8; kc++) {
        short8 ah = *(const short8*)&hp[par][0][arow][kc * 32 + acol];
        short8 am = *(const short8*)&hp[par][1][arow][kc * 32 + acol];
#pragma unroll
        for (int j = 0; j < 4; j++) {
          accr[j] = mfma_(ah, Wvr[j][kc], accr[j]); accr[j] = mfma_(am, Wvr[j][kc], accr[j]);
          accz[j] = mfma_(ah, Wvz[j][kc], accz[j]); accz[j] = mfma_(am, Wvz[j][kc], accz[j]);
        }
      }
#pragma unroll
      for (int j = 0; j < 4; j++)
#pragma unroll
        for (int e = 0; e < 4; e++) {
          int row = q * 4 + e, col = c0 + 16 * j + (lane & 15);
          float gr = accr[j][e] + qr[j][e];
          float gz = accz[j][e] + qz[j][e];
          float h = hf[row][col];
          float hn = cellpw_fast(gr, gz, qn[j][e], h);
          hf[row][col] = hn;
          ushort_t hi = f2bf(hn), mid = f2bf(hn - bf2f(hi));
          hp[t & 1][0][row][col] = hi;
          hp[t & 1][1][row][col] = mid;
          hnv[j][e] = hn;
        }
      __syncthreads();  // orders LDS h1[t] for next step
      if (tid == 0) { if (!fast) __threadfence(); stflag(fg + 24, t + 1); }
      // out[t] HBM stores AFTER the bump: drain overlaps next step
#pragma unroll
      for (int j = 0; j < 4; j++)
#pragma unroll
        for (int e = 0; e < 4; e++) {
          int row = q * 4 + e, col = c0 + 16 * j + (lane & 15);
          out[((size_t)t * B_ + gb + row) * H_ + col] = hnv[j][e];
        }
      ready = fast ? lcheck(rpn, t + 2, ract) : 0;
    }
#pragma unroll
    for (int j = 0; j < 4; j++)
#pragma unroll
      for (int e = 0; e < 4; e++) {
        int row = q * 4 + e, col = c0 + 16 * j + (lane & 15);
        out[(size_t)T_ * B_ * H_ + (size_t)B_ * H_ + (size_t)(gb + row) * H_ + col] =
            hf[row][col];
      }
  }

  // diagnostic sentinel: spin abort signature
  if (tid == 0 && aborted) out[(size_t)gb * H_] = 4096.0f;
}

extern "C" void kernel_launch(void* const* d_in, const int* in_sizes, int n_in,
                              void* d_out, int out_size, void* d_ws, size_t ws_size,
                              hipStream_t stream) {
  const float* x     = (const float*)d_in[0];
  const float* state = (const float*)d_in[1];
  const float* Wi0   = (const float*)d_in[2];
  const float* Wh0   = (const float*)d_in[3];
  const float* Wn0   = (const float*)d_in[4];
  const float* Wi1   = (const float*)d_in[5];
  const float* Wh1   = (const float*)d_in[6];
  const float* Wn1   = (const float*)d_in[7];
  float* out = (float*)d_out;
  uint_t* ws = (uint_t*)d_ws;

  prep_kernel<<<dim3((N_FLAGS + 255) / 256), dim3(256), 0, stream>>>(ws);

  gru_main<<<dim3(80), dim3(256), 0, stream>>>(
      x, Wi0, Wh0, Wn0, Wi1, Wh1, Wn1, state, out, ws, nullptr);
}